// Round 2
// baseline (5333.369 us; speedup 1.0000x reference)
//
#include <hip/hip_runtime.h>
#include <hip/hip_cooperative_groups.h>
#include <math.h>

// B=64, S=128, E=512, H=512, A=256, V=8192, T=32
#define BB 64
#define SS 128
#define EE 512
#define HH 512
#define AA 256
#define VV 8192
#define TT 32

namespace cg = cooperative_groups;

typedef __bf16 bf16x8 __attribute__((ext_vector_type(8)));
typedef __bf16 bf16x4 __attribute__((ext_vector_type(4)));
typedef float  f32x4  __attribute__((ext_vector_type(4)));

__device__ __forceinline__ bf16x8 cvt_v(float4 u, float4 v) {
    bf16x8 r;
    r[0] = (__bf16)u.x; r[1] = (__bf16)u.y; r[2] = (__bf16)u.z; r[3] = (__bf16)u.w;
    r[4] = (__bf16)v.x; r[5] = (__bf16)v.y; r[6] = (__bf16)v.z; r[7] = (__bf16)v.w;
    return r;
}

__device__ __forceinline__ float tanh_fast(float x) {
    x = fminf(15.f, fmaxf(-15.f, x));
    float e = __expf(2.f * x);
    return (e - 1.f) / (e + 1.f);
}
__device__ __forceinline__ float sigmoid_fast(float x) {
    return 1.f / (1.f + __expf(-x));
}

#define LDW(d, p) { const float4* q_ = (const float4*)(p); d##0 = q_[0]; d##1 = q_[1]; d##2 = q_[2]; d##3 = q_[3]; }

// ---------------------------------------------------------------------------
// fp32 GEMM (NN): C[M,N] = A[M,K] * B[K,N]. One-time enc_proj only.
// ---------------------------------------------------------------------------
__global__ __launch_bounds__(256) void gemm_nn(
    const float* __restrict__ A, int lda,
    const float* __restrict__ B, int ldb,
    float* __restrict__ C, int ldc, int K)
{
    __shared__ float As[16][68];
    __shared__ float Bs[16][68];
    const int tid = threadIdx.x;
    const int m0 = blockIdx.x * 64, n0 = blockIdx.y * 64;
    const int row = tid >> 2, kq = (tid & 3) * 4;
    const int kk = tid >> 4, nq = (tid & 15) * 4;
    const int tm = tid >> 4, tn = tid & 15;
    float acc[4][4] = {};
    for (int k0 = 0; k0 < K; k0 += 16) {
        float4 av = *(const float4*)(A + (size_t)(m0 + row) * lda + k0 + kq);
        float4 bv = *(const float4*)(B + (size_t)(k0 + kk) * ldb + n0 + nq);
        As[kq + 0][row] = av.x; As[kq + 1][row] = av.y;
        As[kq + 2][row] = av.z; As[kq + 3][row] = av.w;
        *(float4*)&Bs[kk][nq] = bv;
        __syncthreads();
#pragma unroll
        for (int k = 0; k < 16; ++k) {
            float4 a = *(const float4*)&As[k][tm * 4];
            float4 b = *(const float4*)&Bs[k][tn * 4];
            acc[0][0] += a.x * b.x; acc[0][1] += a.x * b.y; acc[0][2] += a.x * b.z; acc[0][3] += a.x * b.w;
            acc[1][0] += a.y * b.x; acc[1][1] += a.y * b.y; acc[1][2] += a.y * b.z; acc[1][3] += a.y * b.w;
            acc[2][0] += a.z * b.x; acc[2][1] += a.z * b.y; acc[2][2] += a.z * b.z; acc[2][3] += a.z * b.w;
            acc[3][0] += a.w * b.x; acc[3][1] += a.w * b.y; acc[3][2] += a.w * b.z; acc[3][3] += a.w * b.w;
        }
        __syncthreads();
    }
#pragma unroll
    for (int i = 0; i < 4; ++i) {
        float4 r = make_float4(acc[i][0], acc[i][1], acc[i][2], acc[i][3]);
        *(float4*)(C + (size_t)(m0 + tm * 4 + i) * ldc + n0 + tn * 4) = r;
    }
}

// ---------------------------------------------------------------------------
// One-time fp32 -> bf16 conversions (only when workspace is large enough).
// ---------------------------------------------------------------------------
__global__ __launch_bounds__(256) void k_cvt_bf16(
    const float* __restrict__ src, __bf16* __restrict__ dst, size_t n4)
{
    size_t i = (size_t)blockIdx.x * 256 + threadIdx.x;
    if (i < n4) {
        float4 v = *(const float4*)(src + i * 4);
        bf16x4 r;
        r[0] = (__bf16)v.x; r[1] = (__bf16)v.y; r[2] = (__bf16)v.z; r[3] = (__bf16)v.w;
        *(bf16x4*)(dst + i * 4) = r;
    }
}

// Combined gates weight Wg[2048][1536]: row n <-> gate row j=((n&3)<<9)+(n>>2);
// k<512 = W_hh[j], 512..1023 = W_ih[j][512..1023] (ctx), 1024..1535 = W_ih[j][0..511] (emb).
__global__ __launch_bounds__(256) void k_cvt_gates(
    const float* __restrict__ W_ih, const float* __restrict__ W_hh,
    __bf16* __restrict__ Wg)
{
    const int n = blockIdx.x;
    const int j = ((n & 3) << 9) + (n >> 2);
    for (int k = threadIdx.x * 4; k < 1536; k += 1024) {
        const float* src = (k < 512)  ? (W_hh + (size_t)j * 512 + k)
                         : (k < 1024) ? (W_ih + (size_t)j * 1024 + k)
                                      : (W_ih + (size_t)j * 1024 + (k - 1024));
        float4 v = *(const float4*)src;
        bf16x4 r;
        r[0] = (__bf16)v.x; r[1] = (__bf16)v.y; r[2] = (__bf16)v.z; r[3] = (__bf16)v.w;
        *(bf16x4*)(Wg + (size_t)n * 1536 + k) = r;
    }
}

// ===========================================================================
// PERSISTENT cooperative kernel: entire 32-step decode in one launch.
// Grid = 256 blocks x 256 threads (1 block/CU guaranteed co-resident).
// Per step t:
//   Phase A: blocks [0,128): out(t-1) tiles (n0=blk*64, K=1024)
//            blocks [128,192): attention(t), one batch per block
//   grid.sync()
//   Phase B: blocks [0,64): gates tiles (n0=blk*32, K=1536) + LSTM pointwise
//   grid.sync()
// Iteration t=TT runs only out(TT-1) then exits.
// ===========================================================================
struct PP {
    const float* encf; const float* encp; const float* W_dec; const float* b_att;
    const float* v_att; const float* emb; const int* tgt;
    const float* W_ih; const float* W_hh; const float* b_ih; const float* b_hh;
    const float* W_out; const float* b_out;
    const __bf16* Wg; const __bf16* Wo_b;
    float* out; float* hbuf; float* cbuf;
    __bf16* xh0; __bf16* xh1; __bf16* hb0; __bf16* hb1;
};

template<bool BF16W>
__global__ __launch_bounds__(256) void persist(PP p)
{
    cg::grid_group grid = cg::this_grid();
    __shared__ __align__(16) char smem[18432];
    const int blk = blockIdx.x;
    const int tid = threadIdx.x;
    const int wv = tid >> 6, lane = tid & 63;
    const int quad = lane >> 4, l16 = lane & 15;

    for (int t = 0; t <= TT; ++t) {
        const __bf16* hold = (t & 1) ? p.hb1 : p.hb0;   // h_new(t-1) bf16
        __bf16* hnew = (t & 1) ? p.hb0 : p.hb1;
        const __bf16* xhp = ((t + 1) & 1) ? p.xh1 : p.xh0;  // xh_ce(t-1)
        __bf16* xhc = (t & 1) ? p.xh1 : p.xh0;              // xh_ce(t)

        // ------------------------- Phase A -------------------------
        if (blk < 128) {
            if (t >= 1) {
                // logits out(t-1): M=64, N=64 tile at n0, K=1024 = [h|ctx]
                __bf16 (*Bs)[64][72] = (__bf16 (*)[64][72])smem;
                const int n0 = blk * 64;
                const int row = tid >> 2, cq = tid & 3;
                const __bf16* aHp = hold + (size_t)(wv * 16 + l16) * 512 + quad * 8;
                const __bf16* aXp = xhp + (size_t)(wv * 16 + l16) * 1024 + quad * 8;

                f32x4 acc[4] = {{0,0,0,0},{0,0,0,0},{0,0,0,0},{0,0,0,0}};
                bf16x8 aC0 = *(const bf16x8*)aHp, aC1 = *(const bf16x8*)(aHp + 32);
                bf16x8 aN0, aN1;
                float4 wA0, wA1, wA2, wA3, wB0, wB1, wB2, wB3;
                bf16x8 pA0, pA1, pB0, pB1;
                const float*  bsf = nullptr;
                const __bf16* bsb = nullptr;
                if constexpr (BF16W) {
                    bsb = p.Wo_b + (size_t)(n0 + row) * 1024 + cq * 16;
                    const bf16x8* q0 = (const bf16x8*)bsb;        pA0 = q0[0]; pA1 = q0[1];
                    const bf16x8* q1 = (const bf16x8*)(bsb + 64); pB0 = q1[0]; pB1 = q1[1];
                } else {
                    bsf = p.W_out + (size_t)(n0 + row) * 1024 + cq * 16;
                    LDW(wA, bsf); LDW(wB, bsf + 64);
                }
                for (int it = 0; it < 16; ++it) {
                    __bf16* dst = &Bs[it & 1][row][cq * 16];
                    if constexpr (BF16W) {
                        *(bf16x8*)dst       = pA0;
                        *(bf16x8*)(dst + 8) = pA1;
                    } else {
                        *(bf16x8*)dst       = cvt_v(wA0, wA1);
                        *(bf16x8*)(dst + 8) = cvt_v(wA2, wA3);
                    }
                    __syncthreads();
                    if constexpr (BF16W) {
                        pA0 = pB0; pA1 = pB1;
                        if (it + 2 < 16) {
                            const bf16x8* q = (const bf16x8*)(bsb + (it + 2) * 64);
                            pB0 = q[0]; pB1 = q[1];
                        }
                    } else {
                        wA0 = wB0; wA1 = wB1; wA2 = wB2; wA3 = wB3;
                        if (it + 2 < 16) LDW(wB, bsf + (it + 2) * 64);
                    }
                    if (it + 1 < 16) {
                        const int itn = it + 1;
                        const __bf16* ap = (itn < 8) ? (aHp + itn * 64) : (aXp + (itn - 8) * 64);
                        aN0 = *(const bf16x8*)ap; aN1 = *(const bf16x8*)(ap + 32);
                    }
#pragma unroll
                    for (int c = 0; c < 4; ++c) {
                        bf16x8 b0 = *(const bf16x8*)&Bs[it & 1][c * 16 + l16][quad * 8];
                        bf16x8 b1 = *(const bf16x8*)&Bs[it & 1][c * 16 + l16][quad * 8 + 32];
                        acc[c] = __builtin_amdgcn_mfma_f32_16x16x32_bf16(aC0, b0, acc[c], 0, 0, 0);
                        acc[c] = __builtin_amdgcn_mfma_f32_16x16x32_bf16(aC1, b1, acc[c], 0, 0, 0);
                    }
                    aC0 = aN0; aC1 = aN1;
                }
                const int m = wv * 16 + quad * 4;
                const int nb = n0 + l16;
                float* op = p.out + (size_t)(t - 1) * VV + nb;
#pragma unroll
                for (int r = 0; r < 4; ++r) {
                    float* orow = op + (size_t)(m + r) * (TT * VV);
                    orow[ 0] = acc[0][r] + p.b_out[nb +  0];
                    orow[16] = acc[1][r] + p.b_out[nb + 16];
                    orow[32] = acc[2][r] + p.b_out[nb + 32];
                    orow[48] = acc[3][r] + p.b_out[nb + 48];
                }
            }
        } else if (blk < 192) {
            if (t < TT) {
                // attention for batch b, 256 threads
                const int b = blk - 128;
                float* sh   = (float*)smem;   // 512
                float* sdec = sh + 512;       // 256
                float* sv   = sdec + 256;     // 256
                float* sw   = sv + 256;       // 128
                sh[tid] = p.hbuf[(size_t)b * 512 + tid];
                sh[tid + 256] = p.hbuf[(size_t)b * 512 + 256 + tid];
                sv[tid] = p.v_att[tid];
                __syncthreads();
                // dec proj: a = tid, K=512
                {
                    const float* w = p.W_dec + tid;
                    float s = 0.f;
#pragma unroll 8
                    for (int k = 0; k < 512; ++k) s += sh[k] * w[(size_t)k * 256];
                    sdec[tid] = s + p.b_att[tid];
                }
                __syncthreads();
                // scores: 4 waves x 32 s each
                {
                    const float* ep0 = p.encp + ((size_t)b * 128 + wv * 32) * 256;
                    for (int i = 0; i < 32; ++i) {
                        const float* ep = ep0 + (size_t)i * 256;
                        float sum = 0.f;
#pragma unroll
                        for (int c = 0; c < 4; ++c) {
                            int a = lane + 64 * c;
                            sum += tanh_fast(ep[a] + sdec[a]) * sv[a];
                        }
#pragma unroll
                        for (int off = 32; off > 0; off >>= 1) sum += __shfl_down(sum, off);
                        if (lane == 0) sw[wv * 32 + i] = sum;
                    }
                }
                __syncthreads();
                // softmax on wave 0 (64 lanes, 2 scores each)
                if (tid < 64) {
                    float a0 = sw[tid], a1 = sw[tid + 64];
                    float m = fmaxf(a0, a1);
#pragma unroll
                    for (int off = 32; off > 0; off >>= 1) m = fmaxf(m, __shfl_xor(m, off));
                    float e0 = __expf(a0 - m), e1 = __expf(a1 - m);
                    sw[tid] = e0; sw[tid + 64] = e1;
                    float ss = e0 + e1;
#pragma unroll
                    for (int off = 32; off > 0; off >>= 1) ss += __shfl_xor(ss, off);
                    if (tid == 0) sh[0] = ss;
                }
                __syncthreads();
                const float inv = 1.f / sh[0];
                // ctx: 2 outputs per thread
                {
                    const float* ef = p.encf + (size_t)b * (SS * EE) + tid;
                    float cv0 = 0.f, cv1 = 0.f;
#pragma unroll 8
                    for (int s = 0; s < 128; ++s) {
                        float w = sw[s];
                        cv0 += w * ef[(size_t)s * 512];
                        cv1 += w * ef[(size_t)s * 512 + 256];
                    }
                    xhc[(size_t)b * 1024 + tid]       = (__bf16)(cv0 * inv);
                    xhc[(size_t)b * 1024 + 256 + tid] = (__bf16)(cv1 * inv);
                }
                // emb gather
                {
                    const int tok = (t == 0) ? 0 : p.tgt[b * TT + t - 1];
                    const float* em = p.emb + (size_t)tok * 512;
                    xhc[(size_t)b * 1024 + 512 + tid] = (__bf16)em[tid];
                    xhc[(size_t)b * 1024 + 768 + tid] = (__bf16)em[tid + 256];
                }
            }
        }
        __threadfence();
        grid.sync();
        if (t == TT) break;

        // ------------------------- Phase B -------------------------
        if (blk < 64) {
            // gates: M=64, N=32 tile at n0=blk*32, K=1536 = [h|ctx|emb] + LSTM
            __bf16 (*Ws)[32][72] = (__bf16 (*)[32][72])smem;             // 9216 B
            float  (*Cf)[36]     = (float (*)[36])(smem + 9216);         // 9216 B
            const int n0 = blk * 32;
            const int rowW = tid >> 3, kq8 = (tid & 7) * 8;
            const __bf16* rB = nullptr;
            const float *rH = nullptr, *rI = nullptr;
            if constexpr (BF16W) {
                rB = p.Wg + (size_t)(n0 + rowW) * 1536 + kq8;
            } else {
                const int nglob = n0 + rowW;
                const int j = ((nglob & 3) << 9) + (nglob >> 2);
                rH = p.W_hh + (size_t)j * 512;
                rI = p.W_ih + (size_t)j * 1024;
            }
            auto wld = [&](int it) -> bf16x8 {
                if constexpr (BF16W) {
                    return *(const bf16x8*)(rB + it * 64);
                } else {
                    const int k = it * 64 + kq8;
                    const float* s = (k < 512) ? (rH + k)
                                   : (k < 1024 ? rI + k : rI + (k - 1024));
                    const float4* q = (const float4*)s;
                    return cvt_v(q[0], q[1]);
                }
            };
            const __bf16* aHp = hold + (size_t)(wv * 16 + l16) * 512 + quad * 8;
            const __bf16* aXp = xhc + (size_t)(wv * 16 + l16) * 1024 + quad * 8;

            f32x4 acc[2] = {{0,0,0,0},{0,0,0,0}};
            bf16x8 wcur = wld(0), wnxt = wld(1);
            bf16x8 aC0 = *(const bf16x8*)aHp, aC1 = *(const bf16x8*)(aHp + 32);
            bf16x8 aN0, aN1;
            for (int it = 0; it < 24; ++it) {
                *(bf16x8*)&Ws[it & 1][rowW][kq8] = wcur;
                __syncthreads();
                wcur = wnxt;
                if (it + 2 < 24) wnxt = wld(it + 2);
                if (it + 1 < 24) {
                    const int itn = it + 1;
                    const __bf16* ap = (itn < 8) ? (aHp + itn * 64) : (aXp + (itn - 8) * 64);
                    aN0 = *(const bf16x8*)ap; aN1 = *(const bf16x8*)(ap + 32);
                }
#pragma unroll
                for (int c = 0; c < 2; ++c) {
                    bf16x8 b0 = *(const bf16x8*)&Ws[it & 1][c * 16 + l16][quad * 8];
                    bf16x8 b1 = *(const bf16x8*)&Ws[it & 1][c * 16 + l16][quad * 8 + 32];
                    acc[c] = __builtin_amdgcn_mfma_f32_16x16x32_bf16(aC0, b0, acc[c], 0, 0, 0);
                    acc[c] = __builtin_amdgcn_mfma_f32_16x16x32_bf16(aC1, b1, acc[c], 0, 0, 0);
                }
                aC0 = aN0; aC1 = aN1;
            }
            __syncthreads();
#pragma unroll
            for (int r = 0; r < 4; ++r) {
                Cf[wv * 16 + quad * 4 + r][ 0 + l16] = acc[0][r];
                Cf[wv * 16 + quad * 4 + r][16 + l16] = acc[1][r];
            }
            __syncthreads();
            const int U0 = n0 >> 2;   // 8 units per block
#pragma unroll
            for (int pass = 0; pass < 2; ++pass) {
                const int it2 = tid + pass * 256;   // 0..511 = 64 bb x 8 ul
                const int bb = it2 >> 3, ul = it2 & 7;
                const int u = U0 + ul;
                const float gi = Cf[bb][4 * ul + 0] + p.b_ih[u]          + p.b_hh[u];
                const float gf = Cf[bb][4 * ul + 1] + p.b_ih[512 + u]    + p.b_hh[512 + u];
                const float gg2 = Cf[bb][4 * ul + 2] + p.b_ih[1024 + u]  + p.b_hh[1024 + u];
                const float go = Cf[bb][4 * ul + 3] + p.b_ih[1536 + u]   + p.b_hh[1536 + u];
                const float si = sigmoid_fast(gi);
                const float sf = sigmoid_fast(gf);
                const float so = sigmoid_fast(go);
                const float cn = sf * p.cbuf[bb * 512 + u] + si * tanh_fast(gg2);
                const float hn = so * tanh_fast(cn);
                p.cbuf[bb * 512 + u] = cn;
                p.hbuf[bb * 512 + u] = hn;
                hnew[(size_t)bb * 512 + u] = (__bf16)hn;
            }
        }
        __threadfence();
        grid.sync();
    }
}

// ===========================================================================
// Fallback path (round-1 proven kernels), used if cooperative launch fails.
// ===========================================================================
template<bool BF16W>
__global__ __launch_bounds__(1024) void fused_out_attn(
    const __bf16* __restrict__ hA, const __bf16* __restrict__ xA,
    const float*  __restrict__ Wo_f, const __bf16* __restrict__ Wo_b,
    const float*  __restrict__ b_out, float* __restrict__ out, int tprev,
    const float* __restrict__ encf, const float* __restrict__ encp,
    const float* __restrict__ W_dec, const float* __restrict__ b_att,
    const float* __restrict__ v_att, const float* __restrict__ emb,
    const int*   __restrict__ tgt, const float* __restrict__ h,
    __bf16* __restrict__ xh_cur, int t, int nOut)
{
    __shared__ __align__(16) char smem[73728];
    const int tid = threadIdx.x;

    if ((int)blockIdx.x < nOut) {
        const int g = tid >> 8, gtid = tid & 255;
        __bf16 (*Bs)[64][72] = (__bf16 (*)[64][72])(smem + (size_t)g * 18432);
        const int n0 = (int)blockIdx.x * 256 + g * 64;
        const int wv = gtid >> 6, lane = gtid & 63;
        const int quad = lane >> 4, l16 = lane & 15;
        const int row = gtid >> 2, cq = gtid & 3;
        const __bf16* aHp = hA + (size_t)(wv * 16 + l16) * 512 + quad * 8;
        const __bf16* aXp = xA + (size_t)(wv * 16 + l16) * 1024 + quad * 8;

        f32x4 acc[4] = {{0,0,0,0},{0,0,0,0},{0,0,0,0},{0,0,0,0}};
        bf16x8 aC0 = *(const bf16x8*)aHp, aC1 = *(const bf16x8*)(aHp + 32);
        bf16x8 aN0, aN1;
        float4 wA0, wA1, wA2, wA3, wB0, wB1, wB2, wB3;
        bf16x8 pA0, pA1, pB0, pB1;
        const float*  bsf = nullptr;
        const __bf16* bsb = nullptr;
        if constexpr (BF16W) {
            bsb = Wo_b + (size_t)(n0 + row) * 1024 + cq * 16;
            const bf16x8* q0 = (const bf16x8*)bsb;        pA0 = q0[0]; pA1 = q0[1];
            const bf16x8* q1 = (const bf16x8*)(bsb + 64); pB0 = q1[0]; pB1 = q1[1];
        } else {
            bsf = Wo_f + (size_t)(n0 + row) * 1024 + cq * 16;
            LDW(wA, bsf); LDW(wB, bsf + 64);
        }
        for (int it = 0; it < 16; ++it) {
            __bf16* dst = &Bs[it & 1][row][cq * 16];
            if constexpr (BF16W) {
                *(bf16x8*)dst       = pA0;
                *(bf16x8*)(dst + 8) = pA1;
            } else {
                *(bf16x8*)dst       = cvt_v(wA0, wA1);
                *(bf16x8*)(dst + 8) = cvt_v(wA2, wA3);
            }
            __syncthreads();
            if constexpr (BF16W) {
                pA0 = pB0; pA1 = pB1;
                if (it + 2 < 16) {
                    const bf16x8* q = (const bf16x8*)(bsb + (it + 2) * 64);
                    pB0 = q[0]; pB1 = q[1];
                }
            } else {
                wA0 = wB0; wA1 = wB1; wA2 = wB2; wA3 = wB3;
                if (it + 2 < 16) LDW(wB, bsf + (it + 2) * 64);
            }
            if (it + 1 < 16) {
                const int itn = it + 1;
                const __bf16* ap = (itn < 8) ? (aHp + itn * 64) : (aXp + (itn - 8) * 64);
                aN0 = *(const bf16x8*)ap; aN1 = *(const bf16x8*)(ap + 32);
            }
#pragma unroll
            for (int c = 0; c < 4; ++c) {
                bf16x8 b0 = *(const bf16x8*)&Bs[it & 1][c * 16 + l16][quad * 8];
                bf16x8 b1 = *(const bf16x8*)&Bs[it & 1][c * 16 + l16][quad * 8 + 32];
                acc[c] = __builtin_amdgcn_mfma_f32_16x16x32_bf16(aC0, b0, acc[c], 0, 0, 0);
                acc[c] = __builtin_amdgcn_mfma_f32_16x16x32_bf16(aC1, b1, acc[c], 0, 0, 0);
            }
            aC0 = aN0; aC1 = aN1;
        }
        const int m = wv * 16 + quad * 4;
        const int nb = n0 + l16;
        float* op = out + (size_t)tprev * VV + nb;
#pragma unroll
        for (int r = 0; r < 4; ++r) {
            float* orow = op + (size_t)(m + r) * (TT * VV);
            orow[ 0] = acc[0][r] + b_out[nb +  0];
            orow[16] = acc[1][r] + b_out[nb + 16];
            orow[32] = acc[2][r] + b_out[nb + 32];
            orow[48] = acc[3][r] + b_out[nb + 48];
        }
    } else {
        const int b = (int)blockIdx.x - nOut;
        float* sh    = (float*)smem;
        float* sdec  = sh + 512;
        float* sv    = sdec + 256;
        float* sw    = sv + 256;
        float* st    = sw + 128;
        float* part  = st + 128;
        float* cpart = part + 1024;

        if (tid < 512) sh[tid] = h[(size_t)b * 512 + tid];
        else if (tid < 768) sv[tid - 512] = v_att[tid - 512];
        __syncthreads();
        {
            const int a = tid & 255, kq = tid >> 8;
            const float* w = W_dec + (size_t)kq * 128 * 256 + a;
            const float* hp = sh + kq * 128;
            float s = 0.f;
#pragma unroll 8
            for (int k = 0; k < 128; ++k) s += hp[k] * w[(size_t)k * 256];
            part[kq * 256 + a] = s;
        }
        __syncthreads();
        if (tid < 256)
            sdec[tid] = part[tid] + part[256 + tid] + part[512 + tid] + part[768 + tid] + b_att[tid];
        __syncthreads();
        {
            const int wv2 = tid >> 6, lane = tid & 63;
#pragma unroll
            for (int i = 0; i < 8; ++i) {
                const int s = wv2 * 8 + i;
                const float* ep = encp + ((size_t)b * 128 + s) * 256;
                float sum = 0.f;
#pragma unroll
                for (int c = 0; c < 4; ++c) {
                    int a = lane + 64 * c;
                    sum += tanhf(ep[a] + sdec[a]) * sv[a];
                }
#pragma unroll
                for (int off = 32; off > 0; off >>= 1) sum += __shfl_down(sum, off);
                if (lane == 0) sw[s] = sum;
            }
        }
        __syncthreads();
        if (tid < 128) st[tid] = sw[tid];
        __syncthreads();
        for (int off = 64; off > 0; off >>= 1) {
            if (tid < off) st[tid] = fmaxf(st[tid], st[tid + off]);
            __syncthreads();
        }
        const float mx = st[0];
        __syncthreads();
        if (tid < 128) { float ex = expf(sw[tid] - mx); sw[tid] = ex; st[tid] = ex; }
        __syncthreads();
        for (int off = 64; off > 0; off >>= 1) {
            if (tid < off) st[tid] += st[tid + off];
            __syncthreads();
        }
        {
            const int e = tid & 511, half = tid >> 9;
            const float* ef = encf + (size_t)b * (SS * EE) + (size_t)half * 64 * 512 + e;
            const float* wp = sw + half * 64;
            float cv = 0.f;
#pragma unroll 8
            for (int s = 0; s < 64; ++s) cv += wp[s] * ef[(size_t)s * 512];
            cpart[half * 512 + e] = cv;
        }
        __syncthreads();
        const float inv = 1.f / st[0];
        if (tid < 512) {
            xh_cur[(size_t)b * 1024 + tid] = (__bf16)((cpart[tid] + cpart[512 + tid]) * inv);
        } else {
            const int e = tid - 512;
            const int tok = (t == 0) ? 0 : tgt[b * TT + t - 1];
            xh_cur[(size_t)b * 1024 + 512 + e] = (__bf16)emb[(size_t)tok * 512 + e];
        }
    }
}

template<bool BF16W>
__global__ __launch_bounds__(256) void gemm_gates_lstm(
    const __bf16* __restrict__ h_old, const __bf16* __restrict__ xh_ce,
    const float* __restrict__ W_ih, const float* __restrict__ W_hh,
    const __bf16* __restrict__ Wg,
    const float* __restrict__ b_ih, const float* __restrict__ b_hh,
    float* __restrict__ hbuf, float* __restrict__ cbuf,
    __bf16* __restrict__ h_new)
{
    __shared__ __bf16 Bs[2][64][72];
    __shared__ float  Cf[64][68];
    const int tid = threadIdx.x;
    const int n0 = blockIdx.x * 64;
    const int wv = tid >> 6, lane = tid & 63;
    const int quad = lane >> 4, l16 = lane & 15;
    const int row = tid >> 2, cq = tid & 3;
    const int nglob = n0 + row;

    const float*  rH = nullptr;
    const float*  rI = nullptr;
    const __bf16* rB = nullptr;
    if constexpr (BF16W) {
        rB = Wg + (size_t)nglob * 1536 + cq * 16;
    } else {
        const int j = ((nglob & 3) << 9) + (nglob >> 2);
        rH = W_hh + (size_t)j * 512;
        rI = W_ih + (size_t)j * 1024;
    }
    const __bf16* aHp = h_old + (size_t)(wv * 16 + l16) * 512 + quad * 8;
    const __bf16* aXp = xh_ce + (size_t)(wv * 16 + l16) * 1024 + quad * 8;

    f32x4 acc[4] = {{0,0,0,0},{0,0,0,0},{0,0,0,0},{0,0,0,0}};
    auto wsrc = [&](int it) -> const float* {
        const int k = it * 64 + cq * 16;
        if (k < 512)  return rH + k;
        if (k < 1024) return rI + k;
        return rI + (k - 1024);
    };
    float4 wA0, wA1, wA2, wA3, wB0, wB1, wB2, wB3;
    bf16x8 pA0, pA1, pB0, pB1;
    if constexpr (BF16W) {
        const bf16x8* q0 = (const bf16x8*)rB;        pA0 = q0[0]; pA1 = q0[1];
        const bf16x8* q1 = (const bf16x8*)(rB + 64); pB0 = q1[0]; pB1 = q1[1];
    } else {
        LDW(wA, wsrc(0)); LDW(wB, wsrc(1));
    }
    bf16x8 aC0 = *(const bf16x8*)aHp, aC1 = *(const bf16x8*)(aHp + 32);
    bf16x8 aN0, aN1;

    for (int it = 0; it < 24; ++it) {
        __bf16* dst = &Bs[it & 1][row][cq * 16];
        if constexpr (BF16W) {
            *(bf16x8*)dst       = pA0;
            *(bf16x8*)(dst + 8) = pA1;
        } else {
            *(bf16x8*)dst       = cvt_v(wA0, wA1);
            *(bf16x8*)(dst + 8) = cvt_v(wA2, wA3);
        }
        __syncthreads();
        if constexpr (BF16W) {
            pA0 = pB0; pA1 = pB1;
            if (it + 2 < 24) {
                const bf16x8* q = (const bf16x8*)(rB + (it + 2) * 64);
                pB0 = q[0]; pB1 = q[1];
            }
        } else {
            wA0 = wB0; wA1 = wB1; wA2 = wB2; wA3 = wB3;
            if (it + 2 < 24) LDW(wB, wsrc(it + 2));
        }
        if (it + 1 < 24) {
            const int itn = it + 1;
            const __bf16* ap = (itn < 8) ? (aHp + itn * 64) : (aXp + (itn - 8) * 64);
            aN0 = *(const bf16x8*)ap; aN1 = *(const bf16x8*)(ap + 32);
        }
#pragma unroll
        for (int c = 0; c < 4; ++c) {
            bf16x8 b0 = *(const bf16x8*)&Bs[it & 1][c * 16 + l16][quad * 8];
            bf16x8 b1 = *(const bf16x8*)&Bs[it & 1][c * 16 + l16][quad * 8 + 32];
            acc[c] = __builtin_amdgcn_mfma_f32_16x16x32_bf16(aC0, b0, acc[c], 0, 0, 0);
            acc[c] = __builtin_amdgcn_mfma_f32_16x16x32_bf16(aC1, b1, acc[c], 0, 0, 0);
        }
        aC0 = aN0; aC1 = aN1;
    }
    __syncthreads();
#pragma unroll
    for (int r = 0; r < 4; ++r) {
        Cf[wv * 16 + quad * 4 + r][ 0 + l16] = acc[0][r];
        Cf[wv * 16 + quad * 4 + r][16 + l16] = acc[1][r];
        Cf[wv * 16 + quad * 4 + r][32 + l16] = acc[2][r];
        Cf[wv * 16 + quad * 4 + r][48 + l16] = acc[3][r];
    }
    __syncthreads();
    const int U0 = n0 >> 2;
    for (int it = tid; it < 1024; it += 256) {
        const int bb = it >> 4, ul = it & 15;
        const int ug = U0 + ul;
        const float gi = Cf[bb][4 * ul + 0] + b_ih[ug]         + b_hh[ug];
        const float gf = Cf[bb][4 * ul + 1] + b_ih[512 + ug]   + b_hh[512 + ug];
        const float gg = Cf[bb][4 * ul + 2] + b_ih[1024 + ug]  + b_hh[1024 + ug];
        const float go = Cf[bb][4 * ul + 3] + b_ih[1536 + ug]  + b_hh[1536 + ug];
        const float si = 1.f / (1.f + expf(-gi));
        const float sf = 1.f / (1.f + expf(-gf));
        const float so = 1.f / (1.f + expf(-go));
        const float cn = sf * cbuf[bb * 512 + ug] + si * tanhf(gg);
        const float hn = so * tanhf(cn);
        cbuf[bb * 512 + ug] = cn;
        hbuf[bb * 512 + ug] = hn;
        h_new[(size_t)bb * 512 + ug] = (__bf16)hn;
    }
}

// ---------------------------------------------------------------------------
__global__ void k_zero_f(float* p, int n) {
    int i = blockIdx.x * 256 + threadIdx.x;
    if (i < n) p[i] = 0.f;
}
__global__ void k_zero_bf(__bf16* p, int n) {
    int i = blockIdx.x * 256 + threadIdx.x;
    if (i < n) p[i] = (__bf16)0.f;
}

// ---------------------------------------------------------------------------
template<bool BIGW>
static void run_seq(
    const float* encf, const int* tgt, const float* emb,
    const float* W_dec, const float* b_att, const float* v_att,
    const float* W_ih, const float* W_hh, const float* b_ih, const float* b_hh,
    const float* W_out, const float* b_out, float* out,
    float* encp, float* hbuf, float* cbuf,
    __bf16* xh0, __bf16* xh1, __bf16* hb0, __bf16* hb1,
    const __bf16* Wg, const __bf16* Wo_b, hipStream_t stream)
{
    fused_out_attn<BIGW><<<64, 1024, 0, stream>>>(
        hb0, xh0, W_out, Wo_b, b_out, out, 0,
        encf, encp, W_dec, b_att, v_att, emb, tgt, hbuf, xh0, 0, 0);
    gemm_gates_lstm<BIGW><<<32, 256, 0, stream>>>(
        hb0, xh0, W_ih, W_hh, Wg, b_ih, b_hh, hbuf, cbuf, hb1);
    for (int t = 1; t < TT; ++t) {
        __bf16* hold = (t & 1) ? hb1 : hb0;
        __bf16* hnew = (t & 1) ? hb0 : hb1;
        __bf16* xhp  = ((t - 1) & 1) ? xh1 : xh0;
        __bf16* xhc  = (t & 1) ? xh1 : xh0;
        fused_out_attn<BIGW><<<96, 1024, 0, stream>>>(
            hold, xhp, W_out, Wo_b, b_out, out, t - 1,
            encf, encp, W_dec, b_att, v_att, emb, tgt, hbuf, xhc, t, 32);
        gemm_gates_lstm<BIGW><<<32, 256, 0, stream>>>(
            hold, xhc, W_ih, W_hh, Wg, b_ih, b_hh, hbuf, cbuf, hnew);
    }
    fused_out_attn<BIGW><<<32, 1024, 0, stream>>>(
        hb0, xh1, W_out, Wo_b, b_out, out, TT - 1,
        encf, encp, W_dec, b_att, v_att, emb, tgt, hbuf, xh0, 0, 32);
}

// ---------------------------------------------------------------------------
extern "C" void kernel_launch(void* const* d_in, const int* in_sizes, int n_in,
                              void* d_out, int out_size, void* d_ws, size_t ws_size,
                              hipStream_t stream)
{
    (void)in_sizes; (void)n_in; (void)out_size;
    const float* encf  = (const float*)d_in[0];
    const int*   tgt   = (const int*)  d_in[1];
    const float* emb   = (const float*)d_in[2];
    const float* W_enc = (const float*)d_in[3];
    const float* W_dec = (const float*)d_in[4];
    const float* b_att = (const float*)d_in[5];
    const float* v_att = (const float*)d_in[6];
    const float* W_ih  = (const float*)d_in[7];
    const float* W_hh  = (const float*)d_in[8];
    const float* b_ih  = (const float*)d_in[9];
    const float* b_hh  = (const float*)d_in[10];
    const float* W_out = (const float*)d_in[11];
    const float* b_out = (const float*)d_in[12];
    float* out = (float*)d_out;

    float* ws = (float*)d_ws;
    size_t off = 0;
    auto alloc = [&](size_t n) { float* p = ws + off; off += (n + 255) & ~(size_t)255; return p; };
    float*  encp = alloc((size_t)BB * SS * AA);
    float*  hbuf = alloc((size_t)BB * HH);
    float*  cbuf = alloc((size_t)BB * HH);
    __bf16* xh0  = (__bf16*)alloc((size_t)BB * 1024 / 2);
    __bf16* xh1  = (__bf16*)alloc((size_t)BB * 1024 / 2);
    __bf16* hb0  = (__bf16*)alloc((size_t)BB * HH / 2);
    __bf16* hb1  = (__bf16*)alloc((size_t)BB * HH / 2);
    __bf16* Wg   = (__bf16*)alloc((size_t)2048 * 1536 / 2);
    __bf16* Wo_b = (__bf16*)alloc((size_t)VV * 1024 / 2);
    const bool big = off * sizeof(float) <= ws_size;

    k_zero_f<<<(2 * BB * HH + 255) / 256, 256, 0, stream>>>(hbuf, 2 * BB * HH);
    k_zero_bf<<<(BB * HH + 255) / 256, 256, 0, stream>>>(hb0, BB * HH);
    gemm_nn<<<dim3(BB * SS / 64, AA / 64), 256, 0, stream>>>(encf, EE, W_enc, AA, encp, AA, EE);
    if (big) {
        k_cvt_bf16<<<(int)(((size_t)VV * 1024 / 4 + 255) / 256), 256, 0, stream>>>(
            W_out, Wo_b, (size_t)VV * 1024 / 4);
        k_cvt_gates<<<2048, 256, 0, stream>>>(W_ih, W_hh, Wg);
    }

    PP pp;
    pp.encf = encf; pp.encp = encp; pp.W_dec = W_dec; pp.b_att = b_att;
    pp.v_att = v_att; pp.emb = emb; pp.tgt = tgt;
    pp.W_ih = W_ih; pp.W_hh = W_hh; pp.b_ih = b_ih; pp.b_hh = b_hh;
    pp.W_out = W_out; pp.b_out = b_out; pp.Wg = Wg; pp.Wo_b = Wo_b;
    pp.out = out; pp.hbuf = hbuf; pp.cbuf = cbuf;
    pp.xh0 = xh0; pp.xh1 = xh1; pp.hb0 = hb0; pp.hb1 = hb1;
    void* kargs[] = { &pp };

    hipError_t rc;
    if (big) {
        void (*fp)(PP) = persist<true>;
        rc = hipLaunchCooperativeKernel((const void*)fp, dim3(256), dim3(256), kargs, 0, stream);
    } else {
        void (*fp)(PP) = persist<false>;
        rc = hipLaunchCooperativeKernel((const void*)fp, dim3(256), dim3(256), kargs, 0, stream);
    }
    if (rc != hipSuccess) {
        if (big)
            run_seq<true>(encf, tgt, emb, W_dec, b_att, v_att, W_ih, W_hh, b_ih, b_hh,
                          W_out, b_out, out, encp, hbuf, cbuf, xh0, xh1, hb0, hb1,
                          Wg, Wo_b, stream);
        else
            run_seq<false>(encf, tgt, emb, W_dec, b_att, v_att, W_ih, W_hh, b_ih, b_hh,
                           W_out, b_out, out, encp, hbuf, cbuf, xh0, xh1, hb0, hb1,
                           Wg, Wo_b, stream);
    }
}

// Round 3
// 2022.767 us; speedup vs baseline: 2.6367x; 2.6367x over previous
//
#include <hip/hip_runtime.h>
#include <math.h>

// B=64, S=128, E=512, H=512, A=256, V=8192, T=32
#define BB 64
#define SS 128
#define EE 512
#define HH 512
#define AA 256
#define VV 8192
#define TT 32

typedef __bf16 bf16x8 __attribute__((ext_vector_type(8)));
typedef __bf16 bf16x4 __attribute__((ext_vector_type(4)));
typedef float  f32x4  __attribute__((ext_vector_type(4)));

__device__ __forceinline__ bf16x8 cvt_v(float4 u, float4 v) {
    bf16x8 r;
    r[0] = (__bf16)u.x; r[1] = (__bf16)u.y; r[2] = (__bf16)u.z; r[3] = (__bf16)u.w;
    r[4] = (__bf16)v.x; r[5] = (__bf16)v.y; r[6] = (__bf16)v.z; r[7] = (__bf16)v.w;
    return r;
}

__device__ __forceinline__ float tanh_fast(float x) {
    x = fminf(15.f, fmaxf(-15.f, x));
    float e = __expf(2.f * x);
    return (e - 1.f) / (e + 1.f);
}
__device__ __forceinline__ float sigmoid_fast(float x) {
    return 1.f / (1.f + __expf(-x));
}

#define LDW(d, p) { const float4* q_ = (const float4*)(p); d##0 = q_[0]; d##1 = q_[1]; d##2 = q_[2]; d##3 = q_[3]; }

// ---------------------------------------------------------------------------
// fp32 GEMM (NN): C[M,N] = A[M,K] * B[K,N]. One-time enc_proj only.
// ---------------------------------------------------------------------------
__global__ __launch_bounds__(256) void gemm_nn(
    const float* __restrict__ A, int lda,
    const float* __restrict__ B, int ldb,
    float* __restrict__ C, int ldc, int K)
{
    __shared__ float As[16][68];
    __shared__ float Bs[16][68];
    const int tid = threadIdx.x;
    const int m0 = blockIdx.x * 64, n0 = blockIdx.y * 64;
    const int row = tid >> 2, kq = (tid & 3) * 4;
    const int kk = tid >> 4, nq = (tid & 15) * 4;
    const int tm = tid >> 4, tn = tid & 15;
    float acc[4][4] = {};
    for (int k0 = 0; k0 < K; k0 += 16) {
        float4 av = *(const float4*)(A + (size_t)(m0 + row) * lda + k0 + kq);
        float4 bv = *(const float4*)(B + (size_t)(k0 + kk) * ldb + n0 + nq);
        As[kq + 0][row] = av.x; As[kq + 1][row] = av.y;
        As[kq + 2][row] = av.z; As[kq + 3][row] = av.w;
        *(float4*)&Bs[kk][nq] = bv;
        __syncthreads();
#pragma unroll
        for (int k = 0; k < 16; ++k) {
            float4 a = *(const float4*)&As[k][tm * 4];
            float4 b = *(const float4*)&Bs[k][tn * 4];
            acc[0][0] += a.x * b.x; acc[0][1] += a.x * b.y; acc[0][2] += a.x * b.z; acc[0][3] += a.x * b.w;
            acc[1][0] += a.y * b.x; acc[1][1] += a.y * b.y; acc[1][2] += a.y * b.z; acc[1][3] += a.y * b.w;
            acc[2][0] += a.z * b.x; acc[2][1] += a.z * b.y; acc[2][2] += a.z * b.z; acc[2][3] += a.z * b.w;
            acc[3][0] += a.w * b.x; acc[3][1] += a.w * b.y; acc[3][2] += a.w * b.z; acc[3][3] += a.w * b.w;
        }
        __syncthreads();
    }
#pragma unroll
    for (int i = 0; i < 4; ++i) {
        float4 r = make_float4(acc[i][0], acc[i][1], acc[i][2], acc[i][3]);
        *(float4*)(C + (size_t)(m0 + tm * 4 + i) * ldc + n0 + tn * 4) = r;
    }
}

// ---------------------------------------------------------------------------
// One-time fp32 -> bf16 conversions (only when workspace is large enough).
// ---------------------------------------------------------------------------
__global__ __launch_bounds__(256) void k_cvt_bf16(
    const float* __restrict__ src, __bf16* __restrict__ dst, size_t n4)
{
    size_t i = (size_t)blockIdx.x * 256 + threadIdx.x;
    if (i < n4) {
        float4 v = *(const float4*)(src + i * 4);
        bf16x4 r;
        r[0] = (__bf16)v.x; r[1] = (__bf16)v.y; r[2] = (__bf16)v.z; r[3] = (__bf16)v.w;
        *(bf16x4*)(dst + i * 4) = r;
    }
}

// Combined gates weight Wg[2048][1536]: row n <-> gate row j=((n&3)<<9)+(n>>2);
// k<512 = W_hh[j], 512..1023 = W_ih[j][512..1023] (ctx), 1024..1535 = W_ih[j][0..511] (emb).
__global__ __launch_bounds__(256) void k_cvt_gates(
    const float* __restrict__ W_ih, const float* __restrict__ W_hh,
    __bf16* __restrict__ Wg)
{
    const int n = blockIdx.x;
    const int j = ((n & 3) << 9) + (n >> 2);
    for (int k = threadIdx.x * 4; k < 1536; k += 1024) {
        const float* src = (k < 512)  ? (W_hh + (size_t)j * 512 + k)
                         : (k < 1024) ? (W_ih + (size_t)j * 1024 + k)
                                      : (W_ih + (size_t)j * 1024 + (k - 1024));
        float4 v = *(const float4*)src;
        bf16x4 r;
        r[0] = (__bf16)v.x; r[1] = (__bf16)v.y; r[2] = (__bf16)v.z; r[3] = (__bf16)v.w;
        *(bf16x4*)(Wg + (size_t)n * 1536 + k) = r;
    }
}

// ---------------------------------------------------------------------------
// FUSED out(t-1) || attn(t), all-256-thread blocks (wide grid).
//   blocks [0,nOut):     one 64-wide logits tile each (n0 = blk*64, K=1024)
//   blocks [nOut,nOut+64): attention for batch b = blk - nOut
// Normal step: grid 192, nOut=128.  t=0: grid 64, nOut=0.  Final: grid 128, nOut=128.
// ---------------------------------------------------------------------------
template<bool BF16W>
__global__ __launch_bounds__(256) void fused_out_attn(
    const __bf16* __restrict__ hA,     // [64][512]  h_new(t-1) bf16
    const __bf16* __restrict__ xA,     // [64][1024] xh_ce(t-1)
    const float*  __restrict__ Wo_f,   // fp32 fallback
    const __bf16* __restrict__ Wo_b,   // bf16
    const float*  __restrict__ b_out,
    float* __restrict__ out, int tprev,
    const float* __restrict__ encf, const float* __restrict__ encp,
    const float* __restrict__ W_dec, const float* __restrict__ b_att,
    const float* __restrict__ v_att, const float* __restrict__ emb,
    const int*   __restrict__ tgt, const float* __restrict__ h,
    __bf16* __restrict__ xh_cur, int t, int nOut)
{
    __shared__ __align__(16) char smem[18432];
    const int blk = blockIdx.x;
    const int tid = threadIdx.x;
    const int wv = tid >> 6, lane = tid & 63;
    const int quad = lane >> 4, l16 = lane & 15;

    if (blk < nOut) {
        // ---------------- logits tile: M=64, N=64 at n0, K=1024 ----------------
        __bf16 (*Bs)[64][72] = (__bf16 (*)[64][72])smem;
        const int n0 = blk * 64;
        const int row = tid >> 2, cq = tid & 3;
        const __bf16* aHp = hA + (size_t)(wv * 16 + l16) * 512 + quad * 8;
        const __bf16* aXp = xA + (size_t)(wv * 16 + l16) * 1024 + quad * 8;

        f32x4 acc[4] = {{0,0,0,0},{0,0,0,0},{0,0,0,0},{0,0,0,0}};
        bf16x8 aC0 = *(const bf16x8*)aHp, aC1 = *(const bf16x8*)(aHp + 32);
        bf16x8 aN0, aN1;
        float4 wA0, wA1, wA2, wA3, wB0, wB1, wB2, wB3;
        bf16x8 pA0, pA1, pB0, pB1;
        const float*  bsf = nullptr;
        const __bf16* bsb = nullptr;
        if constexpr (BF16W) {
            bsb = Wo_b + (size_t)(n0 + row) * 1024 + cq * 16;
            const bf16x8* q0 = (const bf16x8*)bsb;        pA0 = q0[0]; pA1 = q0[1];
            const bf16x8* q1 = (const bf16x8*)(bsb + 64); pB0 = q1[0]; pB1 = q1[1];
        } else {
            bsf = Wo_f + (size_t)(n0 + row) * 1024 + cq * 16;
            LDW(wA, bsf); LDW(wB, bsf + 64);
        }
        for (int it = 0; it < 16; ++it) {
            __bf16* dst = &Bs[it & 1][row][cq * 16];
            if constexpr (BF16W) {
                *(bf16x8*)dst       = pA0;
                *(bf16x8*)(dst + 8) = pA1;
            } else {
                *(bf16x8*)dst       = cvt_v(wA0, wA1);
                *(bf16x8*)(dst + 8) = cvt_v(wA2, wA3);
            }
            __syncthreads();
            if constexpr (BF16W) {
                pA0 = pB0; pA1 = pB1;
                if (it + 2 < 16) {
                    const bf16x8* q = (const bf16x8*)(bsb + (it + 2) * 64);
                    pB0 = q[0]; pB1 = q[1];
                }
            } else {
                wA0 = wB0; wA1 = wB1; wA2 = wB2; wA3 = wB3;
                if (it + 2 < 16) LDW(wB, bsf + (it + 2) * 64);
            }
            if (it + 1 < 16) {
                const int itn = it + 1;
                const __bf16* ap = (itn < 8) ? (aHp + itn * 64) : (aXp + (itn - 8) * 64);
                aN0 = *(const bf16x8*)ap; aN1 = *(const bf16x8*)(ap + 32);
            }
#pragma unroll
            for (int c = 0; c < 4; ++c) {
                bf16x8 b0 = *(const bf16x8*)&Bs[it & 1][c * 16 + l16][quad * 8];
                bf16x8 b1 = *(const bf16x8*)&Bs[it & 1][c * 16 + l16][quad * 8 + 32];
                acc[c] = __builtin_amdgcn_mfma_f32_16x16x32_bf16(aC0, b0, acc[c], 0, 0, 0);
                acc[c] = __builtin_amdgcn_mfma_f32_16x16x32_bf16(aC1, b1, acc[c], 0, 0, 0);
            }
            aC0 = aN0; aC1 = aN1;
        }
        const int m = wv * 16 + quad * 4;
        const int nb = n0 + l16;
        float* op = out + (size_t)tprev * VV + nb;
#pragma unroll
        for (int r = 0; r < 4; ++r) {
            float* orow = op + (size_t)(m + r) * (TT * VV);
            orow[ 0] = acc[0][r] + b_out[nb +  0];
            orow[16] = acc[1][r] + b_out[nb + 16];
            orow[32] = acc[2][r] + b_out[nb + 32];
            orow[48] = acc[3][r] + b_out[nb + 48];
        }
    } else {
        // ---------------- attention for batch b (256 threads) ----------------
        const int b = blk - nOut;
        float* sh   = (float*)smem;   // 512
        float* sdec = sh + 512;       // 256
        float* sv   = sdec + 256;     // 256
        float* sw   = sv + 256;       // 128
        sh[tid] = h[(size_t)b * 512 + tid];
        sh[tid + 256] = h[(size_t)b * 512 + 256 + tid];
        sv[tid] = v_att[tid];
        __syncthreads();
        // dec proj: a = tid, K=512
        {
            const float* w = W_dec + tid;
            float s = 0.f;
#pragma unroll 8
            for (int k = 0; k < 512; ++k) s += sh[k] * w[(size_t)k * 256];
            sdec[tid] = s + b_att[tid];
        }
        __syncthreads();
        // scores: 4 waves x 32 s each
        {
            const float* ep0 = encp + ((size_t)b * 128 + wv * 32) * 256;
            for (int i = 0; i < 32; ++i) {
                const float* ep = ep0 + (size_t)i * 256;
                float sum = 0.f;
#pragma unroll
                for (int c = 0; c < 4; ++c) {
                    int a = lane + 64 * c;
                    sum += tanh_fast(ep[a] + sdec[a]) * sv[a];
                }
#pragma unroll
                for (int off = 32; off > 0; off >>= 1) sum += __shfl_down(sum, off);
                if (lane == 0) sw[wv * 32 + i] = sum;
            }
        }
        __syncthreads();
        // softmax on wave 0
        if (tid < 64) {
            float a0 = sw[tid], a1 = sw[tid + 64];
            float m = fmaxf(a0, a1);
#pragma unroll
            for (int off = 32; off > 0; off >>= 1) m = fmaxf(m, __shfl_xor(m, off));
            float e0 = __expf(a0 - m), e1 = __expf(a1 - m);
            sw[tid] = e0; sw[tid + 64] = e1;
            float ss = e0 + e1;
#pragma unroll
            for (int off = 32; off > 0; off >>= 1) ss += __shfl_xor(ss, off);
            if (tid == 0) sh[0] = ss;
        }
        __syncthreads();
        const float inv = 1.f / sh[0];
        // ctx
        {
            const float* ef = encf + (size_t)b * (SS * EE) + tid;
            float cv0 = 0.f, cv1 = 0.f;
#pragma unroll 8
            for (int s = 0; s < 128; ++s) {
                float w = sw[s];
                cv0 += w * ef[(size_t)s * 512];
                cv1 += w * ef[(size_t)s * 512 + 256];
            }
            xh_cur[(size_t)b * 1024 + tid]       = (__bf16)(cv0 * inv);
            xh_cur[(size_t)b * 1024 + 256 + tid] = (__bf16)(cv1 * inv);
        }
        // emb gather
        {
            const int tok = (t == 0) ? 0 : tgt[b * TT + t - 1];
            const float* em = emb + (size_t)tok * 512;
            xh_cur[(size_t)b * 1024 + 512 + tid] = (__bf16)em[tid];
            xh_cur[(size_t)b * 1024 + 768 + tid] = (__bf16)em[tid + 256];
        }
    }
}

// ---------------------------------------------------------------------------
// Gates GEMM (bf16 MFMA) + fused LSTM pointwise. Grid 64 x 256thr,
// N=32-wide tiles (n0 = blk*32), K=1536 = [h|ctx|emb].
// ---------------------------------------------------------------------------
template<bool BF16W>
__global__ __launch_bounds__(256) void gemm_gates_lstm(
    const __bf16* __restrict__ h_old,   // [64][512]
    const __bf16* __restrict__ xh_ce,   // [64][1024] = [ctx|emb]
    const float* __restrict__ W_ih, const float* __restrict__ W_hh,
    const __bf16* __restrict__ Wg,      // [2048][1536] pre-permuted bf16
    const float* __restrict__ b_ih, const float* __restrict__ b_hh,
    float* __restrict__ hbuf, float* __restrict__ cbuf,
    __bf16* __restrict__ h_new)
{
    __shared__ __align__(16) char smem[18432];
    __bf16 (*Ws)[32][72] = (__bf16 (*)[32][72])smem;             // 9216 B
    float  (*Cf)[36]     = (float (*)[36])(smem + 9216);         // 9216 B
    const int tid = threadIdx.x;
    const int wv = tid >> 6, lane = tid & 63;
    const int quad = lane >> 4, l16 = lane & 15;
    const int n0 = blockIdx.x * 32;
    const int rowW = tid >> 3, kq8 = (tid & 7) * 8;

    const __bf16* rB = nullptr;
    const float *rH = nullptr, *rI = nullptr;
    if constexpr (BF16W) {
        rB = Wg + (size_t)(n0 + rowW) * 1536 + kq8;
    } else {
        const int nglob = n0 + rowW;
        const int j = ((nglob & 3) << 9) + (nglob >> 2);
        rH = W_hh + (size_t)j * 512;
        rI = W_ih + (size_t)j * 1024;
    }
    auto wld = [&](int it) -> bf16x8 {
        if constexpr (BF16W) {
            return *(const bf16x8*)(rB + it * 64);
        } else {
            const int k = it * 64 + kq8;
            const float* s = (k < 512) ? (rH + k)
                           : (k < 1024 ? rI + k : rI + (k - 1024));
            const float4* q = (const float4*)s;
            return cvt_v(q[0], q[1]);
        }
    };
    const __bf16* aHp = h_old + (size_t)(wv * 16 + l16) * 512 + quad * 8;
    const __bf16* aXp = xh_ce + (size_t)(wv * 16 + l16) * 1024 + quad * 8;

    f32x4 acc[2] = {{0,0,0,0},{0,0,0,0}};
    bf16x8 wcur = wld(0), wnxt = wld(1);
    bf16x8 aC0 = *(const bf16x8*)aHp, aC1 = *(const bf16x8*)(aHp + 32);
    bf16x8 aN0, aN1;
    for (int it = 0; it < 24; ++it) {
        *(bf16x8*)&Ws[it & 1][rowW][kq8] = wcur;
        __syncthreads();
        wcur = wnxt;
        if (it + 2 < 24) wnxt = wld(it + 2);
        if (it + 1 < 24) {
            const int itn = it + 1;
            const __bf16* ap = (itn < 8) ? (aHp + itn * 64) : (aXp + (itn - 8) * 64);
            aN0 = *(const bf16x8*)ap; aN1 = *(const bf16x8*)(ap + 32);
        }
#pragma unroll
        for (int c = 0; c < 2; ++c) {
            bf16x8 b0 = *(const bf16x8*)&Ws[it & 1][c * 16 + l16][quad * 8];
            bf16x8 b1 = *(const bf16x8*)&Ws[it & 1][c * 16 + l16][quad * 8 + 32];
            acc[c] = __builtin_amdgcn_mfma_f32_16x16x32_bf16(aC0, b0, acc[c], 0, 0, 0);
            acc[c] = __builtin_amdgcn_mfma_f32_16x16x32_bf16(aC1, b1, acc[c], 0, 0, 0);
        }
        aC0 = aN0; aC1 = aN1;
    }
    __syncthreads();
#pragma unroll
    for (int r = 0; r < 4; ++r) {
        Cf[wv * 16 + quad * 4 + r][ 0 + l16] = acc[0][r];
        Cf[wv * 16 + quad * 4 + r][16 + l16] = acc[1][r];
    }
    __syncthreads();
    const int U0 = n0 >> 2;   // 8 units per block
#pragma unroll
    for (int pass = 0; pass < 2; ++pass) {
        const int it2 = tid + pass * 256;   // 0..511 = 64 bb x 8 ul
        const int bb = it2 >> 3, ul = it2 & 7;
        const int u = U0 + ul;
        const float gi = Cf[bb][4 * ul + 0] + b_ih[u]          + b_hh[u];
        const float gf = Cf[bb][4 * ul + 1] + b_ih[512 + u]    + b_hh[512 + u];
        const float gg = Cf[bb][4 * ul + 2] + b_ih[1024 + u]   + b_hh[1024 + u];
        const float go = Cf[bb][4 * ul + 3] + b_ih[1536 + u]   + b_hh[1536 + u];
        const float si = sigmoid_fast(gi);
        const float sf = sigmoid_fast(gf);
        const float so = sigmoid_fast(go);
        const float cn = sf * cbuf[bb * 512 + u] + si * tanh_fast(gg);
        const float hn = so * tanh_fast(cn);
        cbuf[bb * 512 + u] = cn;
        hbuf[bb * 512 + u] = hn;
        h_new[(size_t)bb * 512 + u] = (__bf16)hn;
    }
}

// ---------------------------------------------------------------------------
__global__ void k_zero_f(float* p, int n) {
    int i = blockIdx.x * 256 + threadIdx.x;
    if (i < n) p[i] = 0.f;
}
__global__ void k_zero_bf(__bf16* p, int n) {
    int i = blockIdx.x * 256 + threadIdx.x;
    if (i < n) p[i] = (__bf16)0.f;
}

// ---------------------------------------------------------------------------
// Schedule: attn(0); gates(0); for t=1..31: [out(t-1)||attn(t)]; gates(t); out(31)
// ---------------------------------------------------------------------------
template<bool BIGW>
static void run_seq(
    const float* encf, const int* tgt, const float* emb,
    const float* W_dec, const float* b_att, const float* v_att,
    const float* W_ih, const float* W_hh, const float* b_ih, const float* b_hh,
    const float* W_out, const float* b_out, float* out,
    float* encp, float* hbuf, float* cbuf,
    __bf16* xh0, __bf16* xh1, __bf16* hb0, __bf16* hb1,
    const __bf16* Wg, const __bf16* Wo_b, hipStream_t stream)
{
    // t = 0: attention only
    fused_out_attn<BIGW><<<64, 256, 0, stream>>>(
        hb0, xh0, W_out, Wo_b, b_out, out, 0,
        encf, encp, W_dec, b_att, v_att, emb, tgt, hbuf, xh0, 0, 0);
    gemm_gates_lstm<BIGW><<<64, 256, 0, stream>>>(
        hb0, xh0, W_ih, W_hh, Wg, b_ih, b_hh, hbuf, cbuf, hb1);

    for (int t = 1; t < TT; ++t) {
        __bf16* hold = (t & 1) ? hb1 : hb0;   // h_new(t-1)
        __bf16* hnew = (t & 1) ? hb0 : hb1;
        __bf16* xhp  = ((t - 1) & 1) ? xh1 : xh0;
        __bf16* xhc  = (t & 1) ? xh1 : xh0;
        fused_out_attn<BIGW><<<192, 256, 0, stream>>>(
            hold, xhp, W_out, Wo_b, b_out, out, t - 1,
            encf, encp, W_dec, b_att, v_att, emb, tgt, hbuf, xhc, t, 128);
        gemm_gates_lstm<BIGW><<<64, 256, 0, stream>>>(
            hold, xhc, W_ih, W_hh, Wg, b_ih, b_hh, hbuf, cbuf, hnew);
    }

    // final logits for t = 31 (no attention blocks)
    fused_out_attn<BIGW><<<128, 256, 0, stream>>>(
        hb0 /* h_new(31) */, xh1 /* xh_ce(31) */, W_out, Wo_b, b_out, out, TT - 1,
        encf, encp, W_dec, b_att, v_att, emb, tgt, hbuf, xh0, 0, 128);
}

// ---------------------------------------------------------------------------
extern "C" void kernel_launch(void* const* d_in, const int* in_sizes, int n_in,
                              void* d_out, int out_size, void* d_ws, size_t ws_size,
                              hipStream_t stream)
{
    (void)in_sizes; (void)n_in; (void)out_size;
    const float* encf  = (const float*)d_in[0];
    const int*   tgt   = (const int*)  d_in[1];
    const float* emb   = (const float*)d_in[2];
    const float* W_enc = (const float*)d_in[3];
    const float* W_dec = (const float*)d_in[4];
    const float* b_att = (const float*)d_in[5];
    const float* v_att = (const float*)d_in[6];
    const float* W_ih  = (const float*)d_in[7];
    const float* W_hh  = (const float*)d_in[8];
    const float* b_ih  = (const float*)d_in[9];
    const float* b_hh  = (const float*)d_in[10];
    const float* W_out = (const float*)d_in[11];
    const float* b_out = (const float*)d_in[12];
    float* out = (float*)d_out;

    float* ws = (float*)d_ws;
    size_t off = 0;
    auto alloc = [&](size_t n) { float* p = ws + off; off += (n + 255) & ~(size_t)255; return p; };
    float*  encp = alloc((size_t)BB * SS * AA);
    float*  hbuf = alloc((size_t)BB * HH);
    float*  cbuf = alloc((size_t)BB * HH);
    __bf16* xh0  = (__bf16*)alloc((size_t)BB * 1024 / 2);
    __bf16* xh1  = (__bf16*)alloc((size_t)BB * 1024 / 2);
    __bf16* hb0  = (__bf16*)alloc((size_t)BB * HH / 2);
    __bf16* hb1  = (__bf16*)alloc((size_t)BB * HH / 2);
    __bf16* Wg   = (__bf16*)alloc((size_t)2048 * 1536 / 2);
    __bf16* Wo_b = (__bf16*)alloc((size_t)VV * 1024 / 2);
    const bool big = off * sizeof(float) <= ws_size;

    k_zero_f<<<(2 * BB * HH + 255) / 256, 256, 0, stream>>>(hbuf, 2 * BB * HH);
    k_zero_bf<<<(BB * HH + 255) / 256, 256, 0, stream>>>(hb0, BB * HH);
    gemm_nn<<<dim3(BB * SS / 64, AA / 64), 256, 0, stream>>>(encf, EE, W_enc, AA, encp, AA, EE);

    if (big) {
        k_cvt_bf16<<<(int)(((size_t)VV * 1024 / 4 + 255) / 256), 256, 0, stream>>>(
            W_out, Wo_b, (size_t)VV * 1024 / 4);
        k_cvt_gates<<<2048, 256, 0, stream>>>(W_ih, W_hh, Wg);
        run_seq<true>(encf, tgt, emb, W_dec, b_att, v_att, W_ih, W_hh, b_ih, b_hh,
                      W_out, b_out, out, encp, hbuf, cbuf, xh0, xh1, hb0, hb1,
                      Wg, Wo_b, stream);
    } else {
        run_seq<false>(encf, tgt, emb, W_dec, b_att, v_att, W_ih, W_hh, b_ih, b_hh,
                       W_out, b_out, out, encp, hbuf, cbuf, xh0, xh1, hb0, hb1,
                       Wg, Wo_b, stream);
    }
}

// Round 4
// 1174.430 us; speedup vs baseline: 4.5412x; 1.7223x over previous
//
#include <hip/hip_runtime.h>
#include <math.h>

// B=64, S=128, E=512, H=512, A=256, V=8192, T=32
#define BB 64
#define SS 128
#define EE 512
#define HH 512
#define AA 256
#define VV 8192
#define TT 32

typedef __bf16 bf16x8 __attribute__((ext_vector_type(8)));
typedef __bf16 bf16x4 __attribute__((ext_vector_type(4)));
typedef float  f32x4  __attribute__((ext_vector_type(4)));

__device__ __forceinline__ bf16x8 cvt_v(float4 u, float4 v) {
    bf16x8 r;
    r[0] = (__bf16)u.x; r[1] = (__bf16)u.y; r[2] = (__bf16)u.z; r[3] = (__bf16)u.w;
    r[4] = (__bf16)v.x; r[5] = (__bf16)v.y; r[6] = (__bf16)v.z; r[7] = (__bf16)v.w;
    return r;
}

__device__ __forceinline__ float tanh_fast(float x) {
    x = fminf(15.f, fmaxf(-15.f, x));
    float e = __expf(2.f * x);
    return (e - 1.f) / (e + 1.f);
}
__device__ __forceinline__ float sigmoid_fast(float x) {
    return 1.f / (1.f + __expf(-x));
}

#define LDW(d, p) { const float4* q_ = (const float4*)(p); d##0 = q_[0]; d##1 = q_[1]; d##2 = q_[2]; d##3 = q_[3]; }

// ---------------------------------------------------------------------------
// fp32 GEMM (NN): C[M,N] = A[M,K] * B[K,N]. One-time enc_proj only.
// ---------------------------------------------------------------------------
__global__ __launch_bounds__(256) void gemm_nn(
    const float* __restrict__ A, int lda,
    const float* __restrict__ B, int ldb,
    float* __restrict__ C, int ldc, int K)
{
    __shared__ float As[16][68];
    __shared__ float Bs[16][68];
    const int tid = threadIdx.x;
    const int m0 = blockIdx.x * 64, n0 = blockIdx.y * 64;
    const int row = tid >> 2, kq = (tid & 3) * 4;
    const int kk = tid >> 4, nq = (tid & 15) * 4;
    const int tm = tid >> 4, tn = tid & 15;
    float acc[4][4] = {};
    for (int k0 = 0; k0 < K; k0 += 16) {
        float4 av = *(const float4*)(A + (size_t)(m0 + row) * lda + k0 + kq);
        float4 bv = *(const float4*)(B + (size_t)(k0 + kk) * ldb + n0 + nq);
        As[kq + 0][row] = av.x; As[kq + 1][row] = av.y;
        As[kq + 2][row] = av.z; As[kq + 3][row] = av.w;
        *(float4*)&Bs[kk][nq] = bv;
        __syncthreads();
#pragma unroll
        for (int k = 0; k < 16; ++k) {
            float4 a = *(const float4*)&As[k][tm * 4];
            float4 b = *(const float4*)&Bs[k][tn * 4];
            acc[0][0] += a.x * b.x; acc[0][1] += a.x * b.y; acc[0][2] += a.x * b.z; acc[0][3] += a.x * b.w;
            acc[1][0] += a.y * b.x; acc[1][1] += a.y * b.y; acc[1][2] += a.y * b.z; acc[1][3] += a.y * b.w;
            acc[2][0] += a.z * b.x; acc[2][1] += a.z * b.y; acc[2][2] += a.z * b.z; acc[2][3] += a.z * b.w;
            acc[3][0] += a.w * b.x; acc[3][1] += a.w * b.y; acc[3][2] += a.w * b.z; acc[3][3] += a.w * b.w;
        }
        __syncthreads();
    }
#pragma unroll
    for (int i = 0; i < 4; ++i) {
        float4 r = make_float4(acc[i][0], acc[i][1], acc[i][2], acc[i][3]);
        *(float4*)(C + (size_t)(m0 + tm * 4 + i) * ldc + n0 + tn * 4) = r;
    }
}

// ---------------------------------------------------------------------------
// One-time fp32 -> bf16 conversions.
// ---------------------------------------------------------------------------
__global__ __launch_bounds__(256) void k_cvt_bf16(
    const float* __restrict__ src, __bf16* __restrict__ dst, size_t n4)
{
    size_t i = (size_t)blockIdx.x * 256 + threadIdx.x;
    if (i < n4) {
        float4 v = *(const float4*)(src + i * 4);
        bf16x4 r;
        r[0] = (__bf16)v.x; r[1] = (__bf16)v.y; r[2] = (__bf16)v.z; r[3] = (__bf16)v.w;
        *(bf16x4*)(dst + i * 4) = r;
    }
}

// Combined gates weight Wg[2048][1536]: row n <-> gate row j=((n&3)<<9)+(n>>2);
// k<512 = W_hh[j], 512..1023 = W_ih[j][512..1023] (ctx), 1024..1535 = W_ih[j][0..511] (emb).
__global__ __launch_bounds__(256) void k_cvt_gates(
    const float* __restrict__ W_ih, const float* __restrict__ W_hh,
    __bf16* __restrict__ Wg)
{
    const int n = blockIdx.x;
    const int j = ((n & 3) << 9) + (n >> 2);
    for (int k = threadIdx.x * 4; k < 1536; k += 1024) {
        const float* src = (k < 512)  ? (W_hh + (size_t)j * 512 + k)
                         : (k < 1024) ? (W_ih + (size_t)j * 1024 + k)
                                      : (W_ih + (size_t)j * 1024 + (k - 1024));
        float4 v = *(const float4*)src;
        bf16x4 r;
        r[0] = (__bf16)v.x; r[1] = (__bf16)v.y; r[2] = (__bf16)v.z; r[3] = (__bf16)v.w;
        *(bf16x4*)(Wg + (size_t)n * 1536 + k) = r;
    }
}

// ---------------------------------------------------------------------------
// Attention step (standalone, 64 blocks x 1024 thr — round-1-proven body).
// Writes xh_cur = [ctx|emb] bf16 AND ctx into XHN[t*64+b][512..1023].
// ---------------------------------------------------------------------------
__global__ __launch_bounds__(1024) void attn_step(
    const float* __restrict__ encf,   // [64,128,512]
    const float* __restrict__ encp,   // [64,128,256]
    const float* __restrict__ W_dec,  // [512,256]
    const float* __restrict__ b_att,  // [256]
    const float* __restrict__ v_att,  // [256]
    const float* __restrict__ emb,    // [8192,512]
    const int*   __restrict__ tgt,    // [64,32]
    const float* __restrict__ h,      // [64,512] fp32
    __bf16* __restrict__ xh_cur,      // [64,1024]
    __bf16* __restrict__ XHN,         // [2048,1024]
    int t)
{
    const int b = blockIdx.x;
    const int tid = threadIdx.x;
    __shared__ float sh[512];
    __shared__ float sdec[256];
    __shared__ float sv[256];
    __shared__ float sw[128], st[128];
    __shared__ float part[4][256];
    __shared__ float cpart[2][512];

    if (tid < 512) sh[tid] = h[(size_t)b * 512 + tid];
    else if (tid < 768) sv[tid - 512] = v_att[tid - 512];
    __syncthreads();

    // Phase 1: dec[a] = sum_k h[k] W_dec[k,a]  (split-K 4)
    {
        const int a = tid & 255, kq = tid >> 8;
        const float* w = W_dec + (size_t)kq * 128 * 256 + a;
        const float* hp = sh + kq * 128;
        float s = 0.f;
#pragma unroll 8
        for (int k = 0; k < 128; ++k) s += hp[k] * w[(size_t)k * 256];
        part[kq][a] = s;
    }
    __syncthreads();
    if (tid < 256)
        sdec[tid] = part[0][tid] + part[1][tid] + part[2][tid] + part[3][tid] + b_att[tid];
    __syncthreads();

    // Phase 2: scores (16 waves x 8 s)
    {
        const int wv = tid >> 6, lane = tid & 63;
#pragma unroll
        for (int i = 0; i < 8; ++i) {
            const int s = wv * 8 + i;
            const float* ep = encp + ((size_t)b * 128 + s) * 256;
            float sum = 0.f;
#pragma unroll
            for (int c = 0; c < 4; ++c) {
                int a = lane + 64 * c;
                sum += tanh_fast(ep[a] + sdec[a]) * sv[a];
            }
#pragma unroll
            for (int off = 32; off > 0; off >>= 1) sum += __shfl_down(sum, off);
            if (lane == 0) sw[s] = sum;
        }
    }
    __syncthreads();

    // Phase 3: softmax
    if (tid < 128) st[tid] = sw[tid];
    __syncthreads();
    for (int off = 64; off > 0; off >>= 1) {
        if (tid < off) st[tid] = fmaxf(st[tid], st[tid + off]);
        __syncthreads();
    }
    const float mx = st[0];
    __syncthreads();
    if (tid < 128) { float ex = __expf(sw[tid] - mx); sw[tid] = ex; st[tid] = ex; }
    __syncthreads();
    for (int off = 64; off > 0; off >>= 1) {
        if (tid < off) st[tid] += st[tid + off];
        __syncthreads();
    }

    // Phase 4: ctx (split-S 2)
    {
        const int e = tid & 511, half = tid >> 9;
        const float* ef = encf + (size_t)b * (SS * EE) + (size_t)half * 64 * 512 + e;
        const float* wp = sw + half * 64;
        float cv = 0.f;
#pragma unroll 8
        for (int s = 0; s < 64; ++s) cv += wp[s] * ef[(size_t)s * 512];
        cpart[half][e] = cv;
    }
    __syncthreads();
    const float inv = 1.f / st[0];
    if (tid < 512) {
        const __bf16 cv = (__bf16)((cpart[0][tid] + cpart[1][tid]) * inv);
        xh_cur[(size_t)b * 1024 + tid] = cv;
        XHN[(size_t)(t * 64 + b) * 1024 + 512 + tid] = cv;
    } else {
        const int e = tid - 512;
        const int tok = (t == 0) ? 0 : tgt[b * TT + t - 1];
        xh_cur[(size_t)b * 1024 + 512 + e] = (__bf16)emb[(size_t)tok * 512 + e];
    }
}

// ---------------------------------------------------------------------------
// Gates GEMM (bf16 MFMA) + fused LSTM pointwise. Grid 64 x 256thr,
// N=32-wide tiles, K=1536. Also writes h_new into XHN[t*64+b][0..511].
// ---------------------------------------------------------------------------
template<bool BF16W>
__global__ __launch_bounds__(256) void gemm_gates_lstm(
    const __bf16* __restrict__ h_old,   // [64][512]
    const __bf16* __restrict__ xh_ce,   // [64][1024] = [ctx|emb]
    const float* __restrict__ W_ih, const float* __restrict__ W_hh,
    const __bf16* __restrict__ Wg,      // [2048][1536] pre-permuted bf16
    const float* __restrict__ b_ih, const float* __restrict__ b_hh,
    float* __restrict__ hbuf, float* __restrict__ cbuf,
    __bf16* __restrict__ h_new,
    __bf16* __restrict__ XHN, int t)
{
    __shared__ __align__(16) char smem[18432];
    __bf16 (*Ws)[32][72] = (__bf16 (*)[32][72])smem;             // 9216 B
    float  (*Cf)[36]     = (float (*)[36])(smem + 9216);         // 9216 B
    const int tid = threadIdx.x;
    const int wv = tid >> 6, lane = tid & 63;
    const int quad = lane >> 4, l16 = lane & 15;
    const int n0 = blockIdx.x * 32;
    const int rowW = tid >> 3, kq8 = (tid & 7) * 8;

    const __bf16* rB = nullptr;
    const float *rH = nullptr, *rI = nullptr;
    if constexpr (BF16W) {
        rB = Wg + (size_t)(n0 + rowW) * 1536 + kq8;
    } else {
        const int nglob = n0 + rowW;
        const int j = ((nglob & 3) << 9) + (nglob >> 2);
        rH = W_hh + (size_t)j * 512;
        rI = W_ih + (size_t)j * 1024;
    }
    auto wld = [&](int it) -> bf16x8 {
        if constexpr (BF16W) {
            return *(const bf16x8*)(rB + it * 64);
        } else {
            const int k = it * 64 + kq8;
            const float* s = (k < 512) ? (rH + k)
                           : (k < 1024 ? rI + k : rI + (k - 1024));
            const float4* q = (const float4*)s;
            return cvt_v(q[0], q[1]);
        }
    };
    const __bf16* aHp = h_old + (size_t)(wv * 16 + l16) * 512 + quad * 8;
    const __bf16* aXp = xh_ce + (size_t)(wv * 16 + l16) * 1024 + quad * 8;

    f32x4 acc[2] = {{0,0,0,0},{0,0,0,0}};
    bf16x8 wcur = wld(0), wnxt = wld(1);
    bf16x8 aC0 = *(const bf16x8*)aHp, aC1 = *(const bf16x8*)(aHp + 32);
    bf16x8 aN0, aN1;
    for (int it = 0; it < 24; ++it) {
        *(bf16x8*)&Ws[it & 1][rowW][kq8] = wcur;
        __syncthreads();
        wcur = wnxt;
        if (it + 2 < 24) wnxt = wld(it + 2);
        if (it + 1 < 24) {
            const int itn = it + 1;
            const __bf16* ap = (itn < 8) ? (aHp + itn * 64) : (aXp + (itn - 8) * 64);
            aN0 = *(const bf16x8*)ap; aN1 = *(const bf16x8*)(ap + 32);
        }
#pragma unroll
        for (int c = 0; c < 2; ++c) {
            bf16x8 b0 = *(const bf16x8*)&Ws[it & 1][c * 16 + l16][quad * 8];
            bf16x8 b1 = *(const bf16x8*)&Ws[it & 1][c * 16 + l16][quad * 8 + 32];
            acc[c] = __builtin_amdgcn_mfma_f32_16x16x32_bf16(aC0, b0, acc[c], 0, 0, 0);
            acc[c] = __builtin_amdgcn_mfma_f32_16x16x32_bf16(aC1, b1, acc[c], 0, 0, 0);
        }
        aC0 = aN0; aC1 = aN1;
    }
    __syncthreads();
#pragma unroll
    for (int r = 0; r < 4; ++r) {
        Cf[wv * 16 + quad * 4 + r][ 0 + l16] = acc[0][r];
        Cf[wv * 16 + quad * 4 + r][16 + l16] = acc[1][r];
    }
    __syncthreads();
    const int U0 = n0 >> 2;   // 8 units per block
#pragma unroll
    for (int pass = 0; pass < 2; ++pass) {
        const int it2 = tid + pass * 256;   // 0..511 = 64 bb x 8 ul
        const int bb = it2 >> 3, ul = it2 & 7;
        const int u = U0 + ul;
        const float gi = Cf[bb][4 * ul + 0] + b_ih[u]          + b_hh[u];
        const float gf = Cf[bb][4 * ul + 1] + b_ih[512 + u]    + b_hh[512 + u];
        const float gg = Cf[bb][4 * ul + 2] + b_ih[1024 + u]   + b_hh[1024 + u];
        const float go = Cf[bb][4 * ul + 3] + b_ih[1536 + u]   + b_hh[1536 + u];
        const float si = sigmoid_fast(gi);
        const float sf = sigmoid_fast(gf);
        const float so = sigmoid_fast(go);
        const float cn = sf * cbuf[bb * 512 + u] + si * tanh_fast(gg);
        const float hn = so * tanh_fast(cn);
        cbuf[bb * 512 + u] = cn;
        hbuf[bb * 512 + u] = hn;
        const __bf16 hb = (__bf16)hn;
        h_new[(size_t)bb * 512 + u] = hb;
        if (XHN) XHN[(size_t)(t * 64 + bb) * 1024 + u] = hb;
    }
}

// ---------------------------------------------------------------------------
// Batched logits GEMM: C[2048][8192] = XHN[2048][1024] @ W_out^T (+ b_out).
// Grid 2048 x 256thr; blk -> mt = blk&15 (M-tile 128), n0 = (blk>>4)*64.
// Row r = t*64+b  ->  out[b][t][:].
// ---------------------------------------------------------------------------
template<bool BF16W>
__global__ __launch_bounds__(256) void gemm_out_big(
    const __bf16* __restrict__ XHN,
    const float*  __restrict__ Wo_f,
    const __bf16* __restrict__ Wo_b,
    const float*  __restrict__ b_out,
    float* __restrict__ out)
{
    __shared__ __bf16 Bs[2][64][72];
    const int tid = threadIdx.x;
    const int blk = blockIdx.x;
    const int mt = blk & 15;
    const int n0 = (blk >> 4) * 64;
    const int wv = tid >> 6, lane = tid & 63;
    const int quad = lane >> 4, l16 = lane & 15;
    const int row = tid >> 2, cq = tid & 3;

    const __bf16* aP0 = XHN + (size_t)(mt * 128 + wv * 16 + l16) * 1024 + quad * 8;
    const __bf16* aP1 = aP0 + (size_t)64 * 1024;

    f32x4 acc[8] = {{0,0,0,0},{0,0,0,0},{0,0,0,0},{0,0,0,0},
                    {0,0,0,0},{0,0,0,0},{0,0,0,0},{0,0,0,0}};
    float4 wA0, wA1, wA2, wA3, wB0, wB1, wB2, wB3;
    bf16x8 pA0, pA1, pB0, pB1;
    const float*  bsf = nullptr;
    const __bf16* bsb = nullptr;
    if constexpr (BF16W) {
        bsb = Wo_b + (size_t)(n0 + row) * 1024 + cq * 16;
        const bf16x8* q0 = (const bf16x8*)bsb;        pA0 = q0[0]; pA1 = q0[1];
        const bf16x8* q1 = (const bf16x8*)(bsb + 64); pB0 = q1[0]; pB1 = q1[1];
    } else {
        bsf = Wo_f + (size_t)(n0 + row) * 1024 + cq * 16;
        LDW(wA, bsf); LDW(wB, bsf + 64);
    }
    bf16x8 a0C0 = *(const bf16x8*)aP0, a0C1 = *(const bf16x8*)(aP0 + 32);
    bf16x8 a1C0 = *(const bf16x8*)aP1, a1C1 = *(const bf16x8*)(aP1 + 32);
    bf16x8 a0N0, a0N1, a1N0, a1N1;

    for (int it = 0; it < 16; ++it) {
        __bf16* dst = &Bs[it & 1][row][cq * 16];
        if constexpr (BF16W) {
            *(bf16x8*)dst       = pA0;
            *(bf16x8*)(dst + 8) = pA1;
        } else {
            *(bf16x8*)dst       = cvt_v(wA0, wA1);
            *(bf16x8*)(dst + 8) = cvt_v(wA2, wA3);
        }
        __syncthreads();
        if constexpr (BF16W) {
            pA0 = pB0; pA1 = pB1;
            if (it + 2 < 16) {
                const bf16x8* q = (const bf16x8*)(bsb + (it + 2) * 64);
                pB0 = q[0]; pB1 = q[1];
            }
        } else {
            wA0 = wB0; wA1 = wB1; wA2 = wB2; wA3 = wB3;
            if (it + 2 < 16) LDW(wB, bsf + (it + 2) * 64);
        }
        if (it + 1 < 16) {
            const __bf16* ap0 = aP0 + (it + 1) * 64;
            const __bf16* ap1 = aP1 + (it + 1) * 64;
            a0N0 = *(const bf16x8*)ap0; a0N1 = *(const bf16x8*)(ap0 + 32);
            a1N0 = *(const bf16x8*)ap1; a1N1 = *(const bf16x8*)(ap1 + 32);
        }
#pragma unroll
        for (int c = 0; c < 4; ++c) {
            bf16x8 b0 = *(const bf16x8*)&Bs[it & 1][c * 16 + l16][quad * 8];
            bf16x8 b1 = *(const bf16x8*)&Bs[it & 1][c * 16 + l16][quad * 8 + 32];
            acc[c]     = __builtin_amdgcn_mfma_f32_16x16x32_bf16(a0C0, b0, acc[c],     0, 0, 0);
            acc[c]     = __builtin_amdgcn_mfma_f32_16x16x32_bf16(a0C1, b1, acc[c],     0, 0, 0);
            acc[4 + c] = __builtin_amdgcn_mfma_f32_16x16x32_bf16(a1C0, b0, acc[4 + c], 0, 0, 0);
            acc[4 + c] = __builtin_amdgcn_mfma_f32_16x16x32_bf16(a1C1, b1, acc[4 + c], 0, 0, 0);
        }
        a0C0 = a0N0; a0C1 = a0N1; a1C0 = a1N0; a1C1 = a1N1;
    }
    const int nb = n0 + l16;
#pragma unroll
    for (int h2 = 0; h2 < 2; ++h2) {
#pragma unroll
        for (int r = 0; r < 4; ++r) {
            const int rglob = mt * 128 + h2 * 64 + wv * 16 + quad * 4 + r;
            const int tstep = rglob >> 6, bb = rglob & 63;
            float* orow = out + (size_t)bb * (TT * VV) + (size_t)tstep * VV + nb;
            orow[ 0] = acc[h2 * 4 + 0][r] + b_out[nb +  0];
            orow[16] = acc[h2 * 4 + 1][r] + b_out[nb + 16];
            orow[32] = acc[h2 * 4 + 2][r] + b_out[nb + 32];
            orow[48] = acc[h2 * 4 + 3][r] + b_out[nb + 48];
        }
    }
}

// ---------------------------------------------------------------------------
// Fallback (round-3 proven): fused out||attn, 256-thr blocks.
// ---------------------------------------------------------------------------
template<bool BF16W>
__global__ __launch_bounds__(256) void fused_out_attn(
    const __bf16* __restrict__ hA, const __bf16* __restrict__ xA,
    const float*  __restrict__ Wo_f, const __bf16* __restrict__ Wo_b,
    const float*  __restrict__ b_out, float* __restrict__ out, int tprev,
    const float* __restrict__ encf, const float* __restrict__ encp,
    const float* __restrict__ W_dec, const float* __restrict__ b_att,
    const float* __restrict__ v_att, const float* __restrict__ emb,
    const int*   __restrict__ tgt, const float* __restrict__ h,
    __bf16* __restrict__ xh_cur, int t, int nOut)
{
    __shared__ __align__(16) char smem[18432];
    const int blk = blockIdx.x;
    const int tid = threadIdx.x;
    const int wv = tid >> 6, lane = tid & 63;
    const int quad = lane >> 4, l16 = lane & 15;

    if (blk < nOut) {
        __bf16 (*Bs)[64][72] = (__bf16 (*)[64][72])smem;
        const int n0 = blk * 64;
        const int row = tid >> 2, cq = tid & 3;
        const __bf16* aHp = hA + (size_t)(wv * 16 + l16) * 512 + quad * 8;
        const __bf16* aXp = xA + (size_t)(wv * 16 + l16) * 1024 + quad * 8;

        f32x4 acc[4] = {{0,0,0,0},{0,0,0,0},{0,0,0,0},{0,0,0,0}};
        bf16x8 aC0 = *(const bf16x8*)aHp, aC1 = *(const bf16x8*)(aHp + 32);
        bf16x8 aN0, aN1;
        float4 wA0, wA1, wA2, wA3, wB0, wB1, wB2, wB3;
        bf16x8 pA0, pA1, pB0, pB1;
        const float*  bsf = nullptr;
        const __bf16* bsb = nullptr;
        if constexpr (BF16W) {
            bsb = Wo_b + (size_t)(n0 + row) * 1024 + cq * 16;
            const bf16x8* q0 = (const bf16x8*)bsb;        pA0 = q0[0]; pA1 = q0[1];
            const bf16x8* q1 = (const bf16x8*)(bsb + 64); pB0 = q1[0]; pB1 = q1[1];
        } else {
            bsf = Wo_f + (size_t)(n0 + row) * 1024 + cq * 16;
            LDW(wA, bsf); LDW(wB, bsf + 64);
        }
        for (int it = 0; it < 16; ++it) {
            __bf16* dst = &Bs[it & 1][row][cq * 16];
            if constexpr (BF16W) {
                *(bf16x8*)dst       = pA0;
                *(bf16x8*)(dst + 8) = pA1;
            } else {
                *(bf16x8*)dst       = cvt_v(wA0, wA1);
                *(bf16x8*)(dst + 8) = cvt_v(wA2, wA3);
            }
            __syncthreads();
            if constexpr (BF16W) {
                pA0 = pB0; pA1 = pB1;
                if (it + 2 < 16) {
                    const bf16x8* q = (const bf16x8*)(bsb + (it + 2) * 64);
                    pB0 = q[0]; pB1 = q[1];
                }
            } else {
                wA0 = wB0; wA1 = wB1; wA2 = wB2; wA3 = wB3;
                if (it + 2 < 16) LDW(wB, bsf + (it + 2) * 64);
            }
            if (it + 1 < 16) {
                const int itn = it + 1;
                const __bf16* ap = (itn < 8) ? (aHp + itn * 64) : (aXp + (itn - 8) * 64);
                aN0 = *(const bf16x8*)ap; aN1 = *(const bf16x8*)(ap + 32);
            }
#pragma unroll
            for (int c = 0; c < 4; ++c) {
                bf16x8 b0 = *(const bf16x8*)&Bs[it & 1][c * 16 + l16][quad * 8];
                bf16x8 b1 = *(const bf16x8*)&Bs[it & 1][c * 16 + l16][quad * 8 + 32];
                acc[c] = __builtin_amdgcn_mfma_f32_16x16x32_bf16(aC0, b0, acc[c], 0, 0, 0);
                acc[c] = __builtin_amdgcn_mfma_f32_16x16x32_bf16(aC1, b1, acc[c], 0, 0, 0);
            }
            aC0 = aN0; aC1 = aN1;
        }
        const int m = wv * 16 + quad * 4;
        const int nb = n0 + l16;
        float* op = out + (size_t)tprev * VV + nb;
#pragma unroll
        for (int r = 0; r < 4; ++r) {
            float* orow = op + (size_t)(m + r) * (TT * VV);
            orow[ 0] = acc[0][r] + b_out[nb +  0];
            orow[16] = acc[1][r] + b_out[nb + 16];
            orow[32] = acc[2][r] + b_out[nb + 32];
            orow[48] = acc[3][r] + b_out[nb + 48];
        }
    } else {
        const int b = blk - nOut;
        float* sh   = (float*)smem;
        float* sdec = sh + 512;
        float* sv   = sdec + 256;
        float* sw   = sv + 256;
        sh[tid] = h[(size_t)b * 512 + tid];
        sh[tid + 256] = h[(size_t)b * 512 + 256 + tid];
        sv[tid] = v_att[tid];
        __syncthreads();
        {
            const float* w = W_dec + tid;
            float s = 0.f;
#pragma unroll 8
            for (int k = 0; k < 512; ++k) s += sh[k] * w[(size_t)k * 256];
            sdec[tid] = s + b_att[tid];
        }
        __syncthreads();
        {
            const float* ep0 = encp + ((size_t)b * 128 + wv * 32) * 256;
            for (int i = 0; i < 32; ++i) {
                const float* ep = ep0 + (size_t)i * 256;
                float sum = 0.f;
#pragma unroll
                for (int c = 0; c < 4; ++c) {
                    int a = lane + 64 * c;
                    sum += tanh_fast(ep[a] + sdec[a]) * sv[a];
                }
#pragma unroll
                for (int off = 32; off > 0; off >>= 1) sum += __shfl_down(sum, off);
                if (lane == 0) sw[wv * 32 + i] = sum;
            }
        }
        __syncthreads();
        if (tid < 64) {
            float a0 = sw[tid], a1 = sw[tid + 64];
            float m = fmaxf(a0, a1);
#pragma unroll
            for (int off = 32; off > 0; off >>= 1) m = fmaxf(m, __shfl_xor(m, off));
            float e0 = __expf(a0 - m), e1 = __expf(a1 - m);
            sw[tid] = e0; sw[tid + 64] = e1;
            float ss = e0 + e1;
#pragma unroll
            for (int off = 32; off > 0; off >>= 1) ss += __shfl_xor(ss, off);
            if (tid == 0) sh[0] = ss;
        }
        __syncthreads();
        const float inv = 1.f / sh[0];
        {
            const float* ef = encf + (size_t)b * (SS * EE) + tid;
            float cv0 = 0.f, cv1 = 0.f;
#pragma unroll 8
            for (int s = 0; s < 128; ++s) {
                float w = sw[s];
                cv0 += w * ef[(size_t)s * 512];
                cv1 += w * ef[(size_t)s * 512 + 256];
            }
            xh_cur[(size_t)b * 1024 + tid]       = (__bf16)(cv0 * inv);
            xh_cur[(size_t)b * 1024 + 256 + tid] = (__bf16)(cv1 * inv);
        }
        {
            const int tok = (t == 0) ? 0 : tgt[b * TT + t - 1];
            const float* em = emb + (size_t)tok * 512;
            xh_cur[(size_t)b * 1024 + 512 + tid] = (__bf16)em[tid];
            xh_cur[(size_t)b * 1024 + 768 + tid] = (__bf16)em[tid + 256];
        }
    }
}

// ---------------------------------------------------------------------------
__global__ void k_zero_f(float* p, int n) {
    int i = blockIdx.x * 256 + threadIdx.x;
    if (i < n) p[i] = 0.f;
}
__global__ void k_zero_bf(__bf16* p, int n) {
    int i = blockIdx.x * 256 + threadIdx.x;
    if (i < n) p[i] = (__bf16)0.f;
}

// ---------------------------------------------------------------------------
extern "C" void kernel_launch(void* const* d_in, const int* in_sizes, int n_in,
                              void* d_out, int out_size, void* d_ws, size_t ws_size,
                              hipStream_t stream)
{
    (void)in_sizes; (void)n_in; (void)out_size;
    const float* encf  = (const float*)d_in[0];
    const int*   tgt   = (const int*)  d_in[1];
    const float* emb   = (const float*)d_in[2];
    const float* W_enc = (const float*)d_in[3];
    const float* W_dec = (const float*)d_in[4];
    const float* b_att = (const float*)d_in[5];
    const float* v_att = (const float*)d_in[6];
    const float* W_ih  = (const float*)d_in[7];
    const float* W_hh  = (const float*)d_in[8];
    const float* b_ih  = (const float*)d_in[9];
    const float* b_hh  = (const float*)d_in[10];
    const float* W_out = (const float*)d_in[11];
    const float* b_out = (const float*)d_in[12];
    float* out = (float*)d_out;

    float* ws = (float*)d_ws;
    size_t off = 0;
    auto alloc = [&](size_t n) { float* p = ws + off; off += (n + 255) & ~(size_t)255; return p; };
    float*  encp = alloc((size_t)BB * SS * AA);
    float*  hbuf = alloc((size_t)BB * HH);
    float*  cbuf = alloc((size_t)BB * HH);
    __bf16* xh0  = (__bf16*)alloc((size_t)BB * 1024 / 2);
    __bf16* xh1  = (__bf16*)alloc((size_t)BB * 1024 / 2);
    __bf16* hb0  = (__bf16*)alloc((size_t)BB * HH / 2);
    __bf16* hb1  = (__bf16*)alloc((size_t)BB * HH / 2);
    __bf16* XHN  = (__bf16*)alloc((size_t)2048 * 1024 / 2);
    __bf16* Wg   = (__bf16*)alloc((size_t)2048 * 1536 / 2);
    const size_t off1 = off;                                  // level-1 watermark
    __bf16* Wo_b = (__bf16*)alloc((size_t)VV * 1024 / 2);
    const size_t off2 = off;                                  // level-2 watermark

    const int level = (off2 * sizeof(float) <= ws_size) ? 2
                    : (off1 * sizeof(float) <= ws_size) ? 1 : 0;

    k_zero_f<<<(2 * BB * HH + 255) / 256, 256, 0, stream>>>(hbuf, 2 * BB * HH);
    k_zero_bf<<<(BB * HH + 255) / 256, 256, 0, stream>>>(hb0, BB * HH);
    gemm_nn<<<dim3(BB * SS / 64, AA / 64), 256, 0, stream>>>(encf, EE, W_enc, AA, encp, AA, EE);

    if (level >= 1) {
        k_cvt_gates<<<2048, 256, 0, stream>>>(W_ih, W_hh, Wg);
        if (level == 2)
            k_cvt_bf16<<<(int)(((size_t)VV * 1024 / 4 + 255) / 256), 256, 0, stream>>>(
                W_out, Wo_b, (size_t)VV * 1024 / 4);

        for (int t = 0; t < TT; ++t) {
            __bf16* hold = (t & 1) ? hb1 : hb0;
            __bf16* hnew = (t & 1) ? hb0 : hb1;
            attn_step<<<64, 1024, 0, stream>>>(
                encf, encp, W_dec, b_att, v_att, emb, tgt, hbuf, xh0, XHN, t);
            gemm_gates_lstm<true><<<64, 256, 0, stream>>>(
                hold, xh0, W_ih, W_hh, Wg, b_ih, b_hh, hbuf, cbuf, hnew, XHN, t);
        }
        if (level == 2)
            gemm_out_big<true><<<2048, 256, 0, stream>>>(XHN, W_out, Wo_b, b_out, out);
        else
            gemm_out_big<false><<<2048, 256, 0, stream>>>(XHN, W_out, Wo_b, b_out, out);
    } else {
        // Fallback: round-3 proven sequence (fp32 weights, fused out||attn).
        fused_out_attn<false><<<64, 256, 0, stream>>>(
            hb0, xh0, W_out, Wo_b, b_out, out, 0,
            encf, encp, W_dec, b_att, v_att, emb, tgt, hbuf, xh0, 0, 0);
        gemm_gates_lstm<false><<<64, 256, 0, stream>>>(
            hb0, xh0, W_ih, W_hh, Wg, b_ih, b_hh, hbuf, cbuf, hb1, nullptr, 0);
        for (int t = 1; t < TT; ++t) {
            __bf16* hold = (t & 1) ? hb1 : hb0;
            __bf16* hnew = (t & 1) ? hb0 : hb1;
            __bf16* xhp  = ((t - 1) & 1) ? xh1 : xh0;
            __bf16* xhc  = (t & 1) ? xh1 : xh0;
            fused_out_attn<false><<<192, 256, 0, stream>>>(
                hold, xhp, W_out, Wo_b, b_out, out, t - 1,
                encf, encp, W_dec, b_att, v_att, emb, tgt, hbuf, xhc, t, 128);
            gemm_gates_lstm<false><<<64, 256, 0, stream>>>(
                hold, xhc, W_ih, W_hh, Wg, b_ih, b_hh, hbuf, cbuf, hnew, nullptr, 0);
        }
        fused_out_attn<false><<<128, 256, 0, stream>>>(
            hb0, xh1, W_out, Wo_b, b_out, out, TT - 1,
            encf, encp, W_dec, b_att, v_att, emb, tgt, hbuf, xh0, 0, 128);
    }
}